// Round 3
// baseline (297.980 us; speedup 1.0000x reference)
//
#include <hip/hip_runtime.h>

// RandomForest: 131072 samples x 64 feat, 64 trees depth 12, 8-class vote.
//
// R3: L2-BW-bound on scattered node gathers (R2: ~4 GB L2 traffic = 85% of
// L2 ceiling). Fix: one block per CU walks ONE tree at a time -> its 32 KiB
// packed table is L1-resident, gathers become L1 hits. X tile (512 samples,
// 128 KiB, pad-513) in dynamic LDS. Leaf classes packed into level-11 nodes
// (no leaf gathers). Feature stored pre-multiplied as LDS byte offset.

constexpr int kSamples  = 131072;
constexpr int kFeatures = 64;
constexpr int kTrees    = 64;
constexpr int kDepth    = 12;
constexpr int kInternal = (1 << kDepth) - 1;   // 4095
constexpr int kClasses  = 8;

constexpr int SPB  = 512;                       // samples per block == threads
constexpr int XSTR = SPB + 1;                   // 513-dword stride: write conflicts gone
constexpr int XLDS_BYTES = kFeatures * XSTR * 4;  // 131,328 B dynamic LDS

struct Node { float thr; int meta; };           // meta: f*XSTR*4 | leaves<<24 (lvl 11)

__global__ __launch_bounds__(256) void pack_nodes_kernel(
    const int* __restrict__ features, const float* __restrict__ thresholds,
    const int* __restrict__ leaf_values, Node* __restrict__ packed)
{
    int i = blockIdx.x * 256 + threadIdx.x;
    if (i >= kTrees * kInternal) return;
    unsigned t = (unsigned)i / (unsigned)kInternal;
    unsigned n = (unsigned)i - t * (unsigned)kInternal;
    int meta = features[i] * (XSTR * 4);        // LDS byte offset of column f
    if (n >= (unsigned)(kInternal >> 1)) {      // level-11 node: children are leaves
        int lL = leaf_values[(t << kDepth) + (2 * (int)n + 1 - kInternal)];
        int lR = leaf_values[(t << kDepth) + (2 * (int)n + 2 - kInternal)];
        meta |= (lL << 24) | (lR << 27);
    }
    Node nd; nd.thr = thresholds[i]; nd.meta = meta;
    packed[(t << kDepth) + n] = nd;             // stride 4096: base = t<<12
}

__global__ __launch_bounds__(SPB, 2) void forest_kernel(
    const float* __restrict__ X, const Node* __restrict__ nodes,
    int* __restrict__ out)
{
    extern __shared__ float xs[];               // [64][513] feature-major, padded
    const int tid  = threadIdx.x;
    const int base = blockIdx.x * SPB;

    // Stage 128 KiB of X: global reads fully coalesced; LDS write bank =
    // (lane + row) % 32 -> exactly 2-way (free).
    for (int i = tid; i < SPB * kFeatures; i += SPB) {
        float v = X[base * kFeatures + i];
        int f = i & (kFeatures - 1);
        int r = i >> 6;
        xs[f * XSTR + r] = v;
    }
    __syncthreads();

    const char* xrow = (const char*)xs + tid * 4;   // column entry for my sample
    unsigned long long votes = 0ull;

    for (int t = 0; t < kTrees; ++t) {
        const char* tb = (const char*)nodes + (t << 15);  // t * 4096 * 8B
        int n = 0;
        int cls;
        #pragma unroll
        for (int d = 0; d < kDepth; ++d) {
            Node nd = *(const Node*)(tb + (n << 3));       // L1-hit gather (32 KiB table)
            if (d < kDepth - 1) {
                float xv = *(const float*)(xrow + nd.meta);
                n = 2 * n + 1 + (xv > nd.thr ? 1 : 0);
            } else {
                float xv = *(const float*)(xrow + (nd.meta & 0x3FFFF));
                int c = xv > nd.thr ? 1 : 0;
                cls = (nd.meta >> (24 + 3 * c)) & 7;       // leaf class from node word
            }
        }
        votes += 1ull << (cls << 3);
        __syncthreads();   // keep all 8 waves on the same tree => table stays in L1
    }

    // argmax over 8 packed byte-counters; strict '>' keeps smallest class on tie
    int best = 0;
    int bc   = (int)(votes & 0xFFull);
    #pragma unroll
    for (int c = 1; c < kClasses; ++c) {
        int cnt = (int)((votes >> (c * 8)) & 0xFFull);
        if (cnt > bc) { bc = cnt; best = c; }
    }
    out[base + tid] = best;
}

extern "C" void kernel_launch(void* const* d_in, const int* in_sizes, int n_in,
                              void* d_out, int out_size, void* d_ws, size_t ws_size,
                              hipStream_t stream) {
    const float* X          = (const float*)d_in[0];
    const int*   features   = (const int*)d_in[1];
    const float* thresholds = (const float*)d_in[2];
    const int*   leaves     = (const int*)d_in[3];
    int*         out        = (int*)d_out;
    Node*        packed     = (Node*)d_ws;      // 2 MiB

    // Opt in to >64 KiB dynamic LDS (idempotent; not a stream op, capture-safe).
    (void)hipFuncSetAttribute((const void*)forest_kernel,
                              hipFuncAttributeMaxDynamicSharedMemorySize,
                              XLDS_BYTES);

    int pack_grid = (kTrees * kInternal + 255) / 256;
    pack_nodes_kernel<<<pack_grid, 256, 0, stream>>>(features, thresholds, leaves, packed);
    forest_kernel<<<kSamples / SPB, SPB, XLDS_BYTES, stream>>>(X, packed, out);
}

// Round 4
// 155.410 us; speedup vs baseline: 1.9174x; 1.9174x over previous
//
#include <hip/hip_runtime.h>

// RandomForest: 131072 samples x 64 feat, 64 trees depth 12, 8-class vote.
//
// R4 theory: bound by divergent node-gather throughput (TA/L1/L2), not LDS
// conflicts (R2) and not raw L2 BW. So: (1) pack levels 10,11 + 4 leaves
// into ONE 16B struct -> 11 gathers/walk instead of 13, 3x fewer deep-level
// line fills; (2) one 512-thread block per CU + per-window barrier -> a
// single 8-tree L1 window per CU; (3) keep ILP=8 tree chains per thread.
// X tile: 512 samples feature-major stride-513 in 128 KiB dynamic LDS
// (staging + walk reads both 2-way aliased = free).

constexpr int kSamples  = 131072;
constexpr int kFeat     = 64;
constexpr int kTrees    = 64;
constexpr int kInternal = 4095;
constexpr int kClasses  = 8;

constexpr int TPB  = 512;                 // threads = samples per block
constexpr int XSTR = TPB + 1;             // 513-dword stride
constexpr int XLDS_BYTES = kFeat * XSTR * 4;   // 131,328 B dynamic LDS
constexpr int ILP  = 8;                   // tree chains per thread

struct Node8 { float thr; int ofs; };     // ofs = f*2052 = LDS byte offset of column f
struct Sub16 { float thr10, thrL, thrR; unsigned meta; };
// meta bits: f10[0:5] f11L[6:11] f11R[12:17] lv0[18:20] lv1[21:23] lv2[24:26] lv3[27:29]

// Levels 0..9: nodes 0..1022 per tree -> Node8 [tree][1024]
__global__ __launch_bounds__(256) void pack_nodes_kernel(
    const int* __restrict__ features, const float* __restrict__ thresholds,
    Node8* __restrict__ nodesA)
{
    int i = blockIdx.x * 256 + threadIdx.x;           // i over 64*1023
    if (i >= kTrees * 1023) return;
    int t = i / 1023;
    int n = i - t * 1023;                              // 0..1022
    int src = t * kInternal + n;
    Node8 nd;
    nd.thr = thresholds[src];
    int f  = features[src];
    nd.ofs = (f << 11) + (f << 2);                     // f * 2052
    nodesA[(t << 10) + n] = nd;
}

// Level-10 subtrees: node n10=1023+j, its two level-11 children, 4 leaves.
__global__ __launch_bounds__(256) void pack_sub_kernel(
    const int* __restrict__ features, const float* __restrict__ thresholds,
    const int* __restrict__ leaf_values, Sub16* __restrict__ subsA)
{
    int i = blockIdx.x * 256 + threadIdx.x;           // i over 64*1024
    if (i >= kTrees * 1024) return;
    int t = i >> 10;
    int j = i & 1023;
    int n10 = 1023 + j;
    int b   = t * kInternal;
    Sub16 sb;
    sb.thr10 = thresholds[b + n10];
    int nL = 2 * n10 + 1, nR = 2 * n10 + 2;            // level-11 children
    sb.thrL  = thresholds[b + nL];
    sb.thrR  = thresholds[b + nR];
    unsigned f10 = (unsigned)features[b + n10];
    unsigned fL  = (unsigned)features[b + nL];
    unsigned fR  = (unsigned)features[b + nR];
    const int* lv = leaf_values + ((t << 12) + 4 * j); // leaves 4j..4j+3
    sb.meta = f10 | (fL << 6) | (fR << 12)
            | ((unsigned)lv[0] << 18) | ((unsigned)lv[1] << 21)
            | ((unsigned)lv[2] << 24) | ((unsigned)lv[3] << 27);
    subsA[(t << 10) + j] = sb;
}

__global__ __launch_bounds__(TPB, 2) void forest_kernel(
    const float* __restrict__ X,
    const Node8* __restrict__ nodesA,   // [64][1024]
    const Sub16* __restrict__ subsA,    // [64][1024]
    int* __restrict__ out)
{
    extern __shared__ float xs[];                    // [64][513] feature-major
    const int tid  = threadIdx.x;
    const int base = blockIdx.x * TPB;

    // Coalesced float4 staging; LDS write bank = (f+s)%32 -> 2-way (free).
    const float4* X4 = (const float4*)X + (size_t)base * (kFeat / 4);
    for (int i = tid; i < TPB * (kFeat / 4); i += TPB) {
        float4 v = X4[i];
        int s  = i >> 4;                 // sample
        int f0 = (i & 15) * 4;           // first of 4 features
        xs[(f0 + 0) * XSTR + s] = v.x;
        xs[(f0 + 1) * XSTR + s] = v.y;
        xs[(f0 + 2) * XSTR + s] = v.z;
        xs[(f0 + 3) * XSTR + s] = v.w;
    }
    __syncthreads();

    const char* xb = (const char*)xs + (tid << 2);   // + f*2052 per access
    unsigned long long votes = 0ull;

    for (int t0 = 0; t0 < kTrees; t0 += ILP) {
        int n[ILP];
        #pragma unroll
        for (int j = 0; j < ILP; ++j) n[j] = 0;

        #pragma unroll
        for (int d = 0; d < 10; ++d) {               // levels 0..9
            #pragma unroll
            for (int j = 0; j < ILP; ++j) {          // 8 independent chains
                Node8 nd = nodesA[((t0 + j) << 10) + n[j]];
                float xv = *(const float*)(xb + nd.ofs);
                n[j] = 2 * n[j] + 1 + (xv > nd.thr ? 1 : 0);
            }
        }

        #pragma unroll
        for (int j = 0; j < ILP; ++j) {              // levels 10,11 + leaf: ONE 16B gather
            Sub16 sb = subsA[((t0 + j) << 10) + (n[j] - 1023)];
            unsigned m = sb.meta;
            int f10 = m & 63;
            float xv10 = *(const float*)(xb + ((f10 << 11) + (f10 << 2)));
            int c10 = xv10 > sb.thr10 ? 1 : 0;
            float thr11 = c10 ? sb.thrR : sb.thrL;
            unsigned fsel = c10 ? (m >> 12) : (m >> 6);
            int f11 = fsel & 63;
            float xv11 = *(const float*)(xb + ((f11 << 11) + (f11 << 2)));
            int c11 = xv11 > thr11 ? 1 : 0;
            int cls = (m >> (18 + 3 * ((c10 << 1) | c11))) & 7;
            votes += 1ull << (cls << 3);
        }
        __syncthreads();   // keep all 8 waves on the same 8-tree L1 window
    }

    // argmax over 8 packed byte counters; strict '>' keeps smallest class on tie
    int best = 0;
    int bc   = (int)(votes & 0xFFull);
    #pragma unroll
    for (int c = 1; c < kClasses; ++c) {
        int cnt = (int)((votes >> (c * 8)) & 0xFFull);
        if (cnt > bc) { bc = cnt; best = c; }
    }
    out[base + tid] = best;
}

extern "C" void kernel_launch(void* const* d_in, const int* in_sizes, int n_in,
                              void* d_out, int out_size, void* d_ws, size_t ws_size,
                              hipStream_t stream) {
    const float* X          = (const float*)d_in[0];
    const int*   features   = (const int*)d_in[1];
    const float* thresholds = (const float*)d_in[2];
    const int*   leaves     = (const int*)d_in[3];
    int*         out        = (int*)d_out;

    Node8* nodesA = (Node8*)d_ws;                         // 512 KiB
    Sub16* subsA  = (Sub16*)((char*)d_ws + (kTrees << 13)); // +512 KiB, 1 MiB

    (void)hipFuncSetAttribute((const void*)forest_kernel,
                              hipFuncAttributeMaxDynamicSharedMemorySize,
                              XLDS_BYTES);

    pack_nodes_kernel<<<(kTrees * 1023 + 255) / 256, 256, 0, stream>>>(
        features, thresholds, nodesA);
    pack_sub_kernel<<<(kTrees * 1024 + 255) / 256, 256, 0, stream>>>(
        features, thresholds, leaves, subsA);
    forest_kernel<<<kSamples / TPB, TPB, XLDS_BYTES, stream>>>(
        X, nodesA, subsA, out);
}

// Round 5
// 139.751 us; speedup vs baseline: 2.1322x; 1.1121x over previous
//
#include <hip/hip_runtime.h>

// RandomForest: 131072 samples x 64 feat, 64 trees depth 12, 8-class vote.
//
// R5 theory: bound by divergent-gather instruction throughput (~35 cyc per
// wave-gather, 11 per tree-walk in R4). Fixes:
//  (1) Pair packing: each even-level node + its 2 children in ONE 16B struct
//      -> one dwordx4 gather resolves TWO levels. 5 pair-gathers (lvls 0..9)
//      + 1 Sub16 gather (lvls 10,11 + 4 leaf classes) = 6 gathers/walk.
//  (2) XSTR=512: walk X-read bank = s%32 (f-independent, 2-way = free);
//      staging writes xs[f*512+tid] (distinct tid/lane = free).
// Structure kept from R4: 512 thr/block, 256 blocks (1/CU), ILP=8 chains,
// barrier per 8-tree window.

constexpr int kSamples  = 131072;
constexpr int kFeat     = 64;
constexpr int kTrees    = 64;
constexpr int kInternal = 4095;
constexpr int kClasses  = 8;

constexpr int TPB  = 512;
constexpr int XSTR = 512;                        // dwords; f column ofs = f<<11 bytes
constexpr int XLDS_BYTES = kFeat * XSTR * 4;     // 131072 B
constexpr int ILP  = 8;

// Pair p covers levels 2p,2p+1; entries-before offsets {0,1,5,21,85}, 341/tree,
// padded to 512 entries -> tree base = t<<9.
struct Pair  { float thr0, thrL, thrR; unsigned meta; };  // meta: f0|fL<<6|fR<<12
struct Sub16 { float thr10, thrL, thrR; unsigned meta; }; // +lv0..lv3 <<18,21,24,27

__global__ __launch_bounds__(256) void pack_pairs_kernel(
    const int* __restrict__ features, const float* __restrict__ thresholds,
    Pair* __restrict__ pairsA)
{
    int i = blockIdx.x * 256 + threadIdx.x;       // over 64*341
    if (i >= kTrees * 341) return;
    int t = i / 341;
    int e = i - t * 341;
    int p, m;
    if      (e < 1)  { p = 0; m = e; }
    else if (e < 5)  { p = 1; m = e - 1; }
    else if (e < 21) { p = 2; m = e - 5; }
    else if (e < 85) { p = 3; m = e - 21; }
    else             { p = 4; m = e - 85; }
    int g0 = (1 << (2 * p)) - 1 + m;              // global node id at level 2p
    int b  = t * kInternal;
    int gL = 2 * g0 + 1, gR = 2 * g0 + 2;         // level 2p+1 children
    Pair pr;
    pr.thr0 = thresholds[b + g0];
    pr.thrL = thresholds[b + gL];
    pr.thrR = thresholds[b + gR];
    pr.meta = (unsigned)features[b + g0]
            | ((unsigned)features[b + gL] << 6)
            | ((unsigned)features[b + gR] << 12);
    pairsA[(t << 9) + e] = pr;
}

__global__ __launch_bounds__(256) void pack_sub_kernel(
    const int* __restrict__ features, const float* __restrict__ thresholds,
    const int* __restrict__ leaf_values, Sub16* __restrict__ subsA)
{
    int i = blockIdx.x * 256 + threadIdx.x;       // over 64*1024
    if (i >= kTrees * 1024) return;
    int t = i >> 10;
    int j = i & 1023;                              // level-10 local index
    int n10 = 1023 + j;
    int b   = t * kInternal;
    int nL = 2 * n10 + 1, nR = 2 * n10 + 2;
    Sub16 sb;
    sb.thr10 = thresholds[b + n10];
    sb.thrL  = thresholds[b + nL];
    sb.thrR  = thresholds[b + nR];
    const int* lv = leaf_values + ((t << 12) + 4 * j);
    sb.meta = (unsigned)features[b + n10]
            | ((unsigned)features[b + nL] << 6)
            | ((unsigned)features[b + nR] << 12)
            | ((unsigned)lv[0] << 18) | ((unsigned)lv[1] << 21)
            | ((unsigned)lv[2] << 24) | ((unsigned)lv[3] << 27);
    subsA[(t << 10) + j] = sb;
}

__global__ __launch_bounds__(TPB, 2) void forest_kernel(
    const float* __restrict__ X,
    const Pair*  __restrict__ pairsA,   // [64][512] (341 used)
    const Sub16* __restrict__ subsA,    // [64][1024]
    int* __restrict__ out)
{
    extern __shared__ float xs[];                  // [64][512] feature-major
    const int tid  = threadIdx.x;
    const int base = blockIdx.x * TPB;

    // Stage own row: global reads L1-amortized (4 KiB contiguous per wave-
    // instruction); LDS writes at f*512+tid -> bank=tid%32, 2-way (free).
    {
        const float4* Xr = (const float4*)(X + (size_t)(base + tid) * kFeat);
        #pragma unroll
        for (int k = 0; k < kFeat / 4; ++k) {
            float4 v = Xr[k];
            xs[(4 * k + 0) * XSTR + tid] = v.x;
            xs[(4 * k + 1) * XSTR + tid] = v.y;
            xs[(4 * k + 2) * XSTR + tid] = v.z;
            xs[(4 * k + 3) * XSTR + tid] = v.w;
        }
    }
    __syncthreads();

    const char* xb = (const char*)xs + (tid << 2); // + (f<<11) per access
    unsigned long long votes = 0ull;

    // entries-before offsets for pairs 0..4
    const int mofs[5] = {0, 1, 5, 21, 85};

    for (int t0 = 0; t0 < kTrees; t0 += ILP) {
        int m[ILP];
        #pragma unroll
        for (int j = 0; j < ILP; ++j) m[j] = 0;

        #pragma unroll
        for (int p = 0; p < 5; ++p) {              // levels 2p, 2p+1
            #pragma unroll
            for (int j = 0; j < ILP; ++j) {        // 8 independent chains
                Pair pr = pairsA[((t0 + j) << 9) + mofs[p] + m[j]];
                float x0 = *(const float*)(xb + ((pr.meta & 63u) << 11));
                int c0 = x0 > pr.thr0 ? 1 : 0;
                float thr1     = c0 ? pr.thrR : pr.thrL;
                unsigned fsel  = c0 ? (pr.meta >> 12) : (pr.meta >> 6);
                float x1 = *(const float*)(xb + ((fsel & 63u) << 11));
                int c1 = x1 > thr1 ? 1 : 0;
                m[j] = 4 * m[j] + 2 * c0 + c1;
            }
        }

        #pragma unroll
        for (int j = 0; j < ILP; ++j) {            // levels 10,11 + leaf
            Sub16 sb = subsA[((t0 + j) << 10) + m[j]];
            unsigned mt = sb.meta;
            float x0 = *(const float*)(xb + ((mt & 63u) << 11));
            int c0 = x0 > sb.thr10 ? 1 : 0;
            float thr1    = c0 ? sb.thrR : sb.thrL;
            unsigned fsel = c0 ? (mt >> 12) : (mt >> 6);
            float x1 = *(const float*)(xb + ((fsel & 63u) << 11));
            int c1 = x1 > thr1 ? 1 : 0;
            int cls = (mt >> (18 + 3 * ((c0 << 1) | c1))) & 7;
            votes += 1ull << (cls << 3);
        }
        __syncthreads();   // one 8-tree L2 window per CU at a time
    }

    // argmax over 8 packed byte counters; strict '>' keeps smallest class
    int best = 0;
    int bc   = (int)(votes & 0xFFull);
    #pragma unroll
    for (int c = 1; c < kClasses; ++c) {
        int cnt = (int)((votes >> (c * 8)) & 0xFFull);
        if (cnt > bc) { bc = cnt; best = c; }
    }
    out[base + tid] = best;
}

extern "C" void kernel_launch(void* const* d_in, const int* in_sizes, int n_in,
                              void* d_out, int out_size, void* d_ws, size_t ws_size,
                              hipStream_t stream) {
    const float* X          = (const float*)d_in[0];
    const int*   features   = (const int*)d_in[1];
    const float* thresholds = (const float*)d_in[2];
    const int*   leaves     = (const int*)d_in[3];
    int*         out        = (int*)d_out;

    Pair*  pairsA = (Pair*)d_ws;                            // 64*512*16 = 512 KiB
    Sub16* subsA  = (Sub16*)((char*)d_ws + (kTrees << 13)); // +512 KiB, 1 MiB

    (void)hipFuncSetAttribute((const void*)forest_kernel,
                              hipFuncAttributeMaxDynamicSharedMemorySize,
                              XLDS_BYTES);

    pack_pairs_kernel<<<(kTrees * 341 + 255) / 256, 256, 0, stream>>>(
        features, thresholds, pairsA);
    pack_sub_kernel<<<(kTrees * 1024 + 255) / 256, 256, 0, stream>>>(
        features, thresholds, leaves, subsA);
    forest_kernel<<<kSamples / TPB, TPB, XLDS_BYTES, stream>>>(
        X, pairsA, subsA, out);
}